// Round 13
// baseline (306.552 us; speedup 1.0000x reference)
//
#include <hip/hip_runtime.h>
#include <stdint.h>

#define N_NODES   50000
#define N_EDGES   800000
#define IN_DIM    128
#define OUT_DIM   128
#define NUM_RELS  8
#define THREADS   256

typedef _Float16 half_t;
typedef _Float16 half2v __attribute__((ext_vector_type(2)));
typedef _Float16 half8 __attribute__((ext_vector_type(8)));
typedef float floatx4 __attribute__((ext_vector_type(4)));

// ============ plan (round 12 resubmit): FUSED agg+gemm+reduce ============
// h never hits memory. Round-11 accounting: back-end = agg(52us, writes h
// 102MB) + gemm3(52us, reads h + writes partials 51MB) + reduce(~15us).
// Fix: block = 16 dsts; aggregate into 32KB LDS hl[16][1024] (XOR-granule
// swizzle); barrier; MFMA out[16x128] = hl @ Wflat with A-frags direct from
// L2-hot WfT (round-8-passed mapping), B-frags from LDS, C -> out f32.
// 3125x16 = 50000 exactly (no guards). featH lives in ws.
// Front-end (sharded prep/scans/scatter) verbatim from round 11.
// (round-12 bench was an infra failure, same signature as round 5's flake;
//  source re-audited: bounds/swizzle-involution/sync/capture all clean.)

#define NBINS3    N_NODES                         // 50000
#define NB3       ((NBINS3 + 1023) / 1024)        // 49

// ---- ws layout (bytes): h eliminated -> tiny footprint
#define WS_FEATH  0                               // featH: 50000 x 128 f16 (12,800,000)
#define WS_WFT    12800000                        // WfT  : 128 x 1024 f16 (262,144)
#define WS_REC    13062144                        // rec  : N_EDGES uint2 (6,400,000)
#define WS_OFF    19462144                        // off  : 50001 i32 (pad 200,064)
#define WS_BSUM   19662208                        // bsum : 49 i32 (pad 256)
#define WS_NEED   (size_t)19662464

// d_out scratch (25.6MB; dead after scatter, before aggmm writes out)
#define DO_RANK   0                               // rank : N_EDGES i32 (3,200,000)
#define DO_HIST8  3200000                         // hist8: 8 x 50000 i32 (1,600,000)
#define DO_OFF8   4800000                         // off8 : 8 x 50000 i32 (1,600,000)

#define CONV_BLOCKS 3125                          // 800000 threads x 8 halfs
#define RANK_BLOCKS 3125                          // 800000 threads x 1 edge
#define RANK_BASE   (512 + CONV_BLOCKS)           // 3637
#define PREP_BLOCKS (RANK_BASE + RANK_BLOCKS)     // 6762

// ---- prep: WfT transpose (512) + featH convert (3125) + sharded rank (3125)
__global__ void prep_kernel(const float* __restrict__ rel_emb, half_t* __restrict__ WfT,
                            const float* __restrict__ feat, half_t* __restrict__ featH,
                            const int* __restrict__ dst, int* __restrict__ hist8,
                            int* __restrict__ rank) {
    int b = blockIdx.x;
    if (b < 512) {                                 // 8*128*128 exactly
        int t = b * 256 + threadIdx.x;             // t = r*16384 + k*128 + n
        int r = t >> 14, k = (t >> 7) & 127, n = t & 127;
        WfT[(size_t)n * 1024 + r * 128 + k] = (half_t)rel_emb[t];
    } else if (b < RANK_BASE) {
        int t = (b - 512) * 256 + threadIdx.x;     // 0..799999, 8 halfs each
        const float* fb = feat + (size_t)t * 8;
        float4 v0 = *(const float4*)fb;
        float4 v1 = *(const float4*)(fb + 4);
        half8 hv;
        hv[0] = (half_t)v0.x; hv[1] = (half_t)v0.y; hv[2] = (half_t)v0.z; hv[3] = (half_t)v0.w;
        hv[4] = (half_t)v1.x; hv[5] = (half_t)v1.y; hv[6] = (half_t)v1.z; hv[7] = (half_t)v1.w;
        *(half8*)(featH + (size_t)t * 8) = hv;
    } else {
        int i = (b - RANK_BASE) * 256 + threadIdx.x;   // < 800000 exactly
        int s = b & 7;                             // this block's XCD shard (RR assumption)
        rank[i] = atomicAdd(&hist8[s * NBINS3 + dst[i]], 1);
    }
}

// ---- scan1: bsum[b] = sum over 1024 dsts of 8-plane hist (round-11 proven)
__global__ void scan1_kernel(const int* __restrict__ hist8, int* __restrict__ bsum) {
    __shared__ int sh[256];
    int b = blockIdx.x, t = threadIdx.x;
    int i0 = b * 1024 + t * 4;
    int s = 0;
    #pragma unroll
    for (int j = 0; j < 4; j++) {
        int idx = i0 + j;
        if (idx < NBINS3)
            #pragma unroll
            for (int x = 0; x < 8; x++) s += hist8[x * NBINS3 + idx];
    }
    sh[t] = s; __syncthreads();
    for (int o = 128; o > 0; o >>= 1) { if (t < o) sh[t] += sh[t + o]; __syncthreads(); }
    if (t == 0) bsum[b] = sh[0];
}

__global__ void scan2_kernel(int* __restrict__ bsum, int* __restrict__ off) {
    __shared__ int sh[64];
    int t = threadIdx.x;
    int v = (t < NB3) ? bsum[t] : 0;
    sh[t] = v; __syncthreads();
    for (int o = 1; o < 64; o <<= 1) {
        int x = (t >= o) ? sh[t - o] : 0;
        __syncthreads();
        sh[t] += x;
        __syncthreads();
    }
    if (t < NB3) bsum[t] = sh[t] - v;
    if (t == 0) off[NBINS3] = N_EDGES;
}

// ---- scan3: off[d] + per-shard bases off8[x][d] (round-11 proven)
__global__ void scan3_kernel(const int* __restrict__ hist8, const int* __restrict__ boff,
                             int* __restrict__ off, int* __restrict__ off8) {
    __shared__ int sh[256];
    int b = blockIdx.x, t = threadIdx.x;
    int i0 = b * 1024 + t * 4;
    int c[4][8]; int v[4]; int s = 0;
    #pragma unroll
    for (int j = 0; j < 4; j++) {
        int idx = i0 + j; int tot = 0;
        #pragma unroll
        for (int x = 0; x < 8; x++) {
            int cv = (idx < NBINS3) ? hist8[x * NBINS3 + idx] : 0;
            c[j][x] = cv; tot += cv;
        }
        v[j] = tot; s += tot;
    }
    sh[t] = s; __syncthreads();
    for (int o = 1; o < 256; o <<= 1) {
        int x = (t >= o) ? sh[t - o] : 0;
        __syncthreads();
        sh[t] += x;
        __syncthreads();
    }
    int run = sh[t] - s + boff[b];
    #pragma unroll
    for (int j = 0; j < 4; j++) {
        int idx = i0 + j;
        if (idx < NBINS3) {
            off[idx] = run;
            int rx = run;
            #pragma unroll
            for (int x = 0; x < 8; x++) { off8[x * NBINS3 + idx] = rx; rx += c[j][x]; }
        }
        run += v[j];
    }
}

// ---- scatter: atomic-free; shard recomputed from i (round-11 proven)
__global__ __launch_bounds__(THREADS) void scatter_kernel(
    const int* __restrict__ dst, const int* __restrict__ src,
    const int* __restrict__ rel, const float* __restrict__ ew,
    const int* __restrict__ rank, const int* __restrict__ off8,
    uint2* __restrict__ rec) {
    int i = blockIdx.x * 256 + threadIdx.x;        // 3125*256 = 800000 exactly
    int d = dst[i];
    int s = (RANK_BASE + (i >> 8)) & 7;            // == prep rank-block's bid&7
    int pos = off8[s * NBINS3 + d] + rank[i];
    uint2 v;
    v.x = (unsigned)(src[i] * 8 + rel[i]);         // src < 2^19, rel < 8
    v.y = __float_as_uint(ew[i]);
    rec[pos] = v;
}

// ---- FUSED aggmm: 16 dsts/block. Phase 1: aggregate edges -> LDS hl[16][1024]
// (XOR-granule swizzle: half addr = row*1024 + seg*128 + ((granule^(row&7))<<3) + (c&7)).
// Phase 2: out[16x128] = hl @ Wflat; A-frags direct from WfT (round-8-passed),
// B-frags from LDS, C layout = round-8-passed out mapping.
#define FUSE_BLOCKS (N_NODES / 16)                 // 3125, exact
__global__ __launch_bounds__(THREADS) void aggmm_kernel(
    const half_t* __restrict__ featH, const uint2* __restrict__ rec,
    const int* __restrict__ off, const half_t* __restrict__ WfT,
    float* __restrict__ out) {
    __shared__ half_t hl[16 * 1024];               // 32 KB -> 5 blocks/CU
    const int t = threadIdx.x;
    const int wave = t >> 6, lane = t & 63;
    const int d0 = blockIdx.x * 16;

    // ---- phase 1: each wave aggregates 4 dsts (wave-per-dst inner loop, proven)
    const half_t* fb = featH + lane * 2;
    for (int i = 0; i < 4; i++) {
        int row = wave * 4 + i;
        int g = d0 + row;
        int beg = off[g], end = off[g + 1];

        float a0x = 0.f, a0y = 0.f, a1x = 0.f, a1y = 0.f;
        float a2x = 0.f, a2y = 0.f, a3x = 0.f, a3y = 0.f;
        float a4x = 0.f, a4y = 0.f, a5x = 0.f, a5y = 0.f;
        float a6x = 0.f, a6y = 0.f, a7x = 0.f, a7y = 0.f;

#define ACCUM(RE, W, F) do {                                   \
        float wx_ = (W) * (float)(F)[0];                       \
        float wy_ = (W) * (float)(F)[1];                       \
        switch (RE) {                                          \
            case 0: a0x += wx_; a0y += wy_; break;             \
            case 1: a1x += wx_; a1y += wy_; break;             \
            case 2: a2x += wx_; a2y += wy_; break;             \
            case 3: a3x += wx_; a3y += wy_; break;             \
            case 4: a4x += wx_; a4y += wy_; break;             \
            case 5: a5x += wx_; a5y += wy_; break;             \
            case 6: a6x += wx_; a6y += wy_; break;             \
            default: a7x += wx_; a7y += wy_; break;            \
        } } while (0)

        int e = beg;
        for (; e + 4 <= end; e += 4) {             // 4 independent featH reads in flight
            uint2 r0 = rec[e], r1 = rec[e + 1], r2 = rec[e + 2], r3 = rec[e + 3];
            half2v f0 = *(const half2v*)(fb + (size_t)(r0.x >> 3) * 128);
            half2v f1 = *(const half2v*)(fb + (size_t)(r1.x >> 3) * 128);
            half2v f2 = *(const half2v*)(fb + (size_t)(r2.x >> 3) * 128);
            half2v f3 = *(const half2v*)(fb + (size_t)(r3.x >> 3) * 128);
            ACCUM(r0.x & 7, __uint_as_float(r0.y), f0);
            ACCUM(r1.x & 7, __uint_as_float(r1.y), f1);
            ACCUM(r2.x & 7, __uint_as_float(r2.y), f2);
            ACCUM(r3.x & 7, __uint_as_float(r3.y), f3);
        }
        for (; e < end; e++) {
            uint2 r0 = rec[e];
            half2v f0 = *(const half2v*)(fb + (size_t)(r0.x >> 3) * 128);
            ACCUM(r0.x & 7, __uint_as_float(r0.y), f0);
        }
#undef ACCUM

        // swizzled LDS store: col = lane*2 in each 128-col segment r
        half_t* hb = hl + row * 1024 + (((lane >> 2) ^ (row & 7)) << 3) + ((lane * 2) & 7);
        *(half2v*)(hb + 0 * 128) = (half2v){(half_t)a0x, (half_t)a0y};
        *(half2v*)(hb + 1 * 128) = (half2v){(half_t)a1x, (half_t)a1y};
        *(half2v*)(hb + 2 * 128) = (half2v){(half_t)a2x, (half_t)a2y};
        *(half2v*)(hb + 3 * 128) = (half2v){(half_t)a3x, (half_t)a3y};
        *(half2v*)(hb + 4 * 128) = (half2v){(half_t)a4x, (half_t)a4y};
        *(half2v*)(hb + 5 * 128) = (half2v){(half_t)a5x, (half_t)a5y};
        *(half2v*)(hb + 6 * 128) = (half2v){(half_t)a6x, (half_t)a6y};
        *(half2v*)(hb + 7 * 128) = (half2v){(half_t)a7x, (half_t)a7y};
    }
    __syncthreads();

    // ---- phase 2: MFMA. Wave owns 32 out-cols (n0 = wave*32).
    const int q = lane >> 4, l16 = lane & 15;
    const int n0 = wave * 32;
    const half_t* W0 = WfT + (size_t)(n0 + l16) * 1024;        // A row for nt=0
    const half_t* W1 = WfT + (size_t)(n0 + 16 + l16) * 1024;   // A row for nt=1

    floatx4 acc0 = (floatx4){0.f, 0.f, 0.f, 0.f};
    floatx4 acc1 = (floatx4){0.f, 0.f, 0.f, 0.f};

    #pragma unroll 4
    for (int kc = 0; kc < 32; kc++) {
        int k0 = kc * 32 + q * 8;
        int phys = ((kc * 4 + q) & 15) ^ (l16 & 7);
        half8 b  = *(const half8*)(hl + l16 * 1024 + (kc >> 2) * 128 + phys * 8);
        half8 a0 = *(const half8*)(W0 + k0);
        half8 a1 = *(const half8*)(W1 + k0);
        acc0 = __builtin_amdgcn_mfma_f32_16x16x32_f16(a0, b, acc0, 0, 0, 0);
        acc1 = __builtin_amdgcn_mfma_f32_16x16x32_f16(a1, b, acc1, 0, 0, 0);
    }

    // C store (round-8-passed layout): out[(d0+l16)][n0 + nt*16 + q*4 + j]
    float* ob = out + (size_t)(d0 + l16) * 128 + n0 + q * 4;
    float4 v0; v0.x = acc0[0]; v0.y = acc0[1]; v0.z = acc0[2]; v0.w = acc0[3];
    float4 v1; v1.x = acc1[0]; v1.y = acc1[1]; v1.z = acc1[2]; v1.w = acc1[3];
    *(float4*)ob = v0;
    *(float4*)(ob + 16) = v1;
}

// ---- fallback (tiny ws): wave-per-edge direct with atomics
__global__ void naive_kernel(const float* __restrict__ feat, const float* __restrict__ rel_emb,
                             const float* __restrict__ ew, const int* __restrict__ src,
                             const int* __restrict__ dst, const int* __restrict__ rel,
                             float* __restrict__ out) {
    int wave = (blockIdx.x * blockDim.x + threadIdx.x) >> 6;
    int lane = threadIdx.x & 63;
    if (wave >= N_EDGES) return;
    const float* f = feat + (size_t)src[wave] * IN_DIM;
    const float* W = rel_emb + (size_t)rel[wave] * IN_DIM * OUT_DIM;
    float w = ew[wave];
    float a0 = 0.f, a1 = 0.f;
    for (int k = 0; k < IN_DIM; k++) {
        float fv = f[k];
        a0 += fv * W[k * OUT_DIM + lane];
        a1 += fv * W[k * OUT_DIM + 64 + lane];
    }
    int d = dst[wave];
    atomicAdd(&out[(size_t)d * OUT_DIM + lane], a0 * w);
    atomicAdd(&out[(size_t)d * OUT_DIM + 64 + lane], a1 * w);
}

extern "C" void kernel_launch(void* const* d_in, const int* in_sizes, int n_in,
                              void* d_out, int out_size, void* d_ws, size_t ws_size,
                              hipStream_t stream) {
    const float* feat    = (const float*)d_in[0];
    const float* rel_emb = (const float*)d_in[1];
    const float* ew      = (const float*)d_in[2];
    const int*   src     = (const int*)d_in[3];
    const int*   dst     = (const int*)d_in[4];
    const int*   rel     = (const int*)d_in[5];
    float* out = (float*)d_out;

    if (ws_size >= WS_NEED) {
        char* ws = (char*)d_ws;
        half_t* featH = (half_t*)(ws + WS_FEATH);
        half_t* WfT   = (half_t*)(ws + WS_WFT);
        uint2*  rec   = (uint2*)(ws + WS_REC);
        int*    off   = (int*)(ws + WS_OFF);
        int*    bsum  = (int*)(ws + WS_BSUM);
        // d_out scratch (dead after scatter; aggmm then writes out)
        int*    rank  = (int*)((char*)d_out + DO_RANK);
        int*    hist8 = (int*)((char*)d_out + DO_HIST8);
        int*    off8  = (int*)((char*)d_out + DO_OFF8);

        hipMemsetAsync(hist8, 0, (size_t)8 * NBINS3 * 4, stream);
        prep_kernel<<<PREP_BLOCKS, THREADS, 0, stream>>>(rel_emb, WfT, feat, featH,
                                                         dst, hist8, rank);
        scan1_kernel<<<NB3, 256, 0, stream>>>(hist8, bsum);
        scan2_kernel<<<1, 64, 0, stream>>>(bsum, off);
        scan3_kernel<<<NB3, 256, 0, stream>>>(hist8, bsum, off, off8);
        scatter_kernel<<<RANK_BLOCKS, THREADS, 0, stream>>>(dst, src, rel, ew,
                                                            rank, off8, rec);
        aggmm_kernel<<<FUSE_BLOCKS, THREADS, 0, stream>>>(featH, rec, off, WfT, out);
    } else {
        hipMemsetAsync(d_out, 0, (size_t)out_size * sizeof(float), stream);
        const long long total = (long long)N_EDGES * 64;
        const int blocks = (int)((total + THREADS - 1) / THREADS);
        naive_kernel<<<blocks, THREADS, 0, stream>>>(feat, rel_emb, ew, src, dst, rel, out);
    }
}

// Round 14
// 274.810 us; speedup vs baseline: 1.1155x; 1.1155x over previous
//
#include <hip/hip_runtime.h>
#include <stdint.h>

#define N_NODES   50000
#define N_EDGES   800000
#define IN_DIM    128
#define OUT_DIM   128
#define NUM_RELS  8
#define THREADS   256
#define AGG_THREADS 1024

typedef _Float16 half_t;
typedef _Float16 half2v __attribute__((ext_vector_type(2)));
typedef _Float16 half8 __attribute__((ext_vector_type(8)));
typedef float floatx4 __attribute__((ext_vector_type(4)));

// ============ plan (round 14): fused aggmm, 1024-thread wave-per-dst ============
// Round-13 lesson: 256-thread fused blocks ran phase-1 as 4 waves x serial
// 4-dst loop -> 12500 waves, HBM 650GB/s (standalone agg: 50000 waves,
// 3.67TB/s). Latency-bound phases live on wave count. Fix: 1024-thread
// blocks, 16 waves, WAVE-PER-DST phase 1 (= proven agg geometry, 50000
// waves, 32 waves/CU); phase 2: waves 0-7 each one 16x16 MFMA tile
// (n0=w*16, K=1024), B from LDS (same swizzle, row=l16), A from L2-hot
// WfT, C = round-8-proven mapping; waves 8-15 retire.
// Front-end (sharded prep/scans/scatter) verbatim from rounds 11-13.

#define NBINS3    N_NODES                         // 50000
#define NB3       ((NBINS3 + 1023) / 1024)        // 49

// ---- ws layout (bytes)
#define WS_FEATH  0                               // featH: 50000 x 128 f16 (12,800,000)
#define WS_WFT    12800000                        // WfT  : 128 x 1024 f16 (262,144)
#define WS_REC    13062144                        // rec  : N_EDGES uint2 (6,400,000)
#define WS_OFF    19462144                        // off  : 50001 i32 (pad 200,064)
#define WS_BSUM   19662208                        // bsum : 49 i32 (pad 256)
#define WS_NEED   (size_t)19662464

// d_out scratch (25.6MB; dead after scatter, before aggmm writes out)
#define DO_RANK   0                               // rank : N_EDGES i32 (3,200,000)
#define DO_HIST8  3200000                         // hist8: 8 x 50000 i32 (1,600,000)
#define DO_OFF8   4800000                         // off8 : 8 x 50000 i32 (1,600,000)

#define CONV_BLOCKS 3125                          // 800000 threads x 8 halfs
#define RANK_BLOCKS 3125                          // 800000 threads x 1 edge
#define RANK_BASE   (512 + CONV_BLOCKS)           // 3637
#define PREP_BLOCKS (RANK_BASE + RANK_BLOCKS)     // 6762

// ---- prep: WfT transpose (512) + featH convert (3125) + sharded rank (3125)
__global__ void prep_kernel(const float* __restrict__ rel_emb, half_t* __restrict__ WfT,
                            const float* __restrict__ feat, half_t* __restrict__ featH,
                            const int* __restrict__ dst, int* __restrict__ hist8,
                            int* __restrict__ rank) {
    int b = blockIdx.x;
    if (b < 512) {                                 // 8*128*128 exactly
        int t = b * 256 + threadIdx.x;             // t = r*16384 + k*128 + n
        int r = t >> 14, k = (t >> 7) & 127, n = t & 127;
        WfT[(size_t)n * 1024 + r * 128 + k] = (half_t)rel_emb[t];
    } else if (b < RANK_BASE) {
        int t = (b - 512) * 256 + threadIdx.x;     // 0..799999, 8 halfs each
        const float* fb = feat + (size_t)t * 8;
        float4 v0 = *(const float4*)fb;
        float4 v1 = *(const float4*)(fb + 4);
        half8 hv;
        hv[0] = (half_t)v0.x; hv[1] = (half_t)v0.y; hv[2] = (half_t)v0.z; hv[3] = (half_t)v0.w;
        hv[4] = (half_t)v1.x; hv[5] = (half_t)v1.y; hv[6] = (half_t)v1.z; hv[7] = (half_t)v1.w;
        *(half8*)(featH + (size_t)t * 8) = hv;
    } else {
        int i = (b - RANK_BASE) * 256 + threadIdx.x;   // < 800000 exactly
        int s = b & 7;                             // this block's XCD shard (RR assumption)
        rank[i] = atomicAdd(&hist8[s * NBINS3 + dst[i]], 1);
    }
}

// ---- scan1: bsum[b] = sum over 1024 dsts of 8-plane hist (round-11 proven)
__global__ void scan1_kernel(const int* __restrict__ hist8, int* __restrict__ bsum) {
    __shared__ int sh[256];
    int b = blockIdx.x, t = threadIdx.x;
    int i0 = b * 1024 + t * 4;
    int s = 0;
    #pragma unroll
    for (int j = 0; j < 4; j++) {
        int idx = i0 + j;
        if (idx < NBINS3)
            #pragma unroll
            for (int x = 0; x < 8; x++) s += hist8[x * NBINS3 + idx];
    }
    sh[t] = s; __syncthreads();
    for (int o = 128; o > 0; o >>= 1) { if (t < o) sh[t] += sh[t + o]; __syncthreads(); }
    if (t == 0) bsum[b] = sh[0];
}

__global__ void scan2_kernel(int* __restrict__ bsum, int* __restrict__ off) {
    __shared__ int sh[64];
    int t = threadIdx.x;
    int v = (t < NB3) ? bsum[t] : 0;
    sh[t] = v; __syncthreads();
    for (int o = 1; o < 64; o <<= 1) {
        int x = (t >= o) ? sh[t - o] : 0;
        __syncthreads();
        sh[t] += x;
        __syncthreads();
    }
    if (t < NB3) bsum[t] = sh[t] - v;
    if (t == 0) off[NBINS3] = N_EDGES;
}

// ---- scan3: off[d] + per-shard bases off8[x][d] (round-11 proven)
__global__ void scan3_kernel(const int* __restrict__ hist8, const int* __restrict__ boff,
                             int* __restrict__ off, int* __restrict__ off8) {
    __shared__ int sh[256];
    int b = blockIdx.x, t = threadIdx.x;
    int i0 = b * 1024 + t * 4;
    int c[4][8]; int v[4]; int s = 0;
    #pragma unroll
    for (int j = 0; j < 4; j++) {
        int idx = i0 + j; int tot = 0;
        #pragma unroll
        for (int x = 0; x < 8; x++) {
            int cv = (idx < NBINS3) ? hist8[x * NBINS3 + idx] : 0;
            c[j][x] = cv; tot += cv;
        }
        v[j] = tot; s += tot;
    }
    sh[t] = s; __syncthreads();
    for (int o = 1; o < 256; o <<= 1) {
        int x = (t >= o) ? sh[t - o] : 0;
        __syncthreads();
        sh[t] += x;
        __syncthreads();
    }
    int run = sh[t] - s + boff[b];
    #pragma unroll
    for (int j = 0; j < 4; j++) {
        int idx = i0 + j;
        if (idx < NBINS3) {
            off[idx] = run;
            int rx = run;
            #pragma unroll
            for (int x = 0; x < 8; x++) { off8[x * NBINS3 + idx] = rx; rx += c[j][x]; }
        }
        run += v[j];
    }
}

// ---- scatter: atomic-free; shard recomputed from i (round-11 proven)
__global__ __launch_bounds__(THREADS) void scatter_kernel(
    const int* __restrict__ dst, const int* __restrict__ src,
    const int* __restrict__ rel, const float* __restrict__ ew,
    const int* __restrict__ rank, const int* __restrict__ off8,
    uint2* __restrict__ rec) {
    int i = blockIdx.x * 256 + threadIdx.x;        // 3125*256 = 800000 exactly
    int d = dst[i];
    int s = (RANK_BASE + (i >> 8)) & 7;            // == prep rank-block's bid&7
    int pos = off8[s * NBINS3 + d] + rank[i];
    uint2 v;
    v.x = (unsigned)(src[i] * 8 + rel[i]);         // src < 2^19, rel < 8
    v.y = __float_as_uint(ew[i]);
    rec[pos] = v;
}

// ---- FUSED aggmm (1024 threads, 16 waves): wave-per-dst agg -> LDS -> MFMA.
// LDS swizzle (both sides, row = hl-row): half addr =
//   row*1024 + seg*128 + ((granule ^ (row&7))<<3) + (c&7),  granule = logical col>>3.
#define FUSE_BLOCKS (N_NODES / 16)                 // 3125, exact
__global__ __launch_bounds__(AGG_THREADS, 8) void aggmm_kernel(
    const half_t* __restrict__ featH, const uint2* __restrict__ rec,
    const int* __restrict__ off, const half_t* __restrict__ WfT,
    float* __restrict__ out) {
    __shared__ half_t hl[16 * 1024];               // 32 KB -> 2 blocks/CU (thread-cap)
    const int t = threadIdx.x;
    const int wave = t >> 6, lane = t & 63;
    const int d0 = blockIdx.x * 16;

    // ---- phase 1: wave w aggregates dst d0+w (proven wave-per-dst geometry)
    {
        const half_t* fb = featH + lane * 2;
        const int row = wave;
        int g = d0 + row;
        int beg = off[g], end = off[g + 1];

        float a0x = 0.f, a0y = 0.f, a1x = 0.f, a1y = 0.f;
        float a2x = 0.f, a2y = 0.f, a3x = 0.f, a3y = 0.f;
        float a4x = 0.f, a4y = 0.f, a5x = 0.f, a5y = 0.f;
        float a6x = 0.f, a6y = 0.f, a7x = 0.f, a7y = 0.f;

#define ACCUM(RE, W, F) do {                                   \
        float wx_ = (W) * (float)(F)[0];                       \
        float wy_ = (W) * (float)(F)[1];                       \
        switch (RE) {                                          \
            case 0: a0x += wx_; a0y += wy_; break;             \
            case 1: a1x += wx_; a1y += wy_; break;             \
            case 2: a2x += wx_; a2y += wy_; break;             \
            case 3: a3x += wx_; a3y += wy_; break;             \
            case 4: a4x += wx_; a4y += wy_; break;             \
            case 5: a5x += wx_; a5y += wy_; break;             \
            case 6: a6x += wx_; a6y += wy_; break;             \
            default: a7x += wx_; a7y += wy_; break;            \
        } } while (0)

        int e = beg;
        for (; e + 4 <= end; e += 4) {             // 4 independent featH reads in flight
            uint2 r0 = rec[e], r1 = rec[e + 1], r2 = rec[e + 2], r3 = rec[e + 3];
            half2v f0 = *(const half2v*)(fb + (size_t)(r0.x >> 3) * 128);
            half2v f1 = *(const half2v*)(fb + (size_t)(r1.x >> 3) * 128);
            half2v f2 = *(const half2v*)(fb + (size_t)(r2.x >> 3) * 128);
            half2v f3 = *(const half2v*)(fb + (size_t)(r3.x >> 3) * 128);
            ACCUM(r0.x & 7, __uint_as_float(r0.y), f0);
            ACCUM(r1.x & 7, __uint_as_float(r1.y), f1);
            ACCUM(r2.x & 7, __uint_as_float(r2.y), f2);
            ACCUM(r3.x & 7, __uint_as_float(r3.y), f3);
        }
        for (; e < end; e++) {
            uint2 r0 = rec[e];
            half2v f0 = *(const half2v*)(fb + (size_t)(r0.x >> 3) * 128);
            ACCUM(r0.x & 7, __uint_as_float(r0.y), f0);
        }
#undef ACCUM

        // swizzled LDS store: logical col = lane*2 within each 128-col segment r
        half_t* hb = hl + row * 1024 + (((lane >> 2) ^ (row & 7)) << 3) + ((lane * 2) & 7);
        *(half2v*)(hb + 0 * 128) = (half2v){(half_t)a0x, (half_t)a0y};
        *(half2v*)(hb + 1 * 128) = (half2v){(half_t)a1x, (half_t)a1y};
        *(half2v*)(hb + 2 * 128) = (half2v){(half_t)a2x, (half_t)a2y};
        *(half2v*)(hb + 3 * 128) = (half2v){(half_t)a3x, (half_t)a3y};
        *(half2v*)(hb + 4 * 128) = (half2v){(half_t)a4x, (half_t)a4y};
        *(half2v*)(hb + 5 * 128) = (half2v){(half_t)a5x, (half_t)a5y};
        *(half2v*)(hb + 6 * 128) = (half2v){(half_t)a6x, (half_t)a6y};
        *(half2v*)(hb + 7 * 128) = (half2v){(half_t)a7x, (half_t)a7y};
    }
    __syncthreads();

    // ---- phase 2: waves 0-7 each compute one 16x16 out tile; waves 8-15 retire
    if (wave < 8) {
        const int q = lane >> 4, l16 = lane & 15;
        const int n0 = wave * 16;
        const half_t* W0 = WfT + (size_t)(n0 + l16) * 1024;    // A row = out col

        floatx4 acc0 = (floatx4){0.f, 0.f, 0.f, 0.f};

        #pragma unroll 4
        for (int kc = 0; kc < 32; kc++) {
            int k0 = kc * 32 + q * 8;
            int phys = ((kc * 4 + q) & 15) ^ (l16 & 7);        // read row = l16
            half8 b  = *(const half8*)(hl + l16 * 1024 + (kc >> 2) * 128 + phys * 8);
            half8 a0 = *(const half8*)(W0 + k0);
            acc0 = __builtin_amdgcn_mfma_f32_16x16x32_f16(a0, b, acc0, 0, 0, 0);
        }

        // C store (round-8-proven layout): out[(d0+l16)][n0 + q*4 + j]
        float* ob = out + (size_t)(d0 + l16) * 128 + n0 + q * 4;
        float4 v0; v0.x = acc0[0]; v0.y = acc0[1]; v0.z = acc0[2]; v0.w = acc0[3];
        *(float4*)ob = v0;
    }
}

// ---- fallback (tiny ws): wave-per-edge direct with atomics
__global__ void naive_kernel(const float* __restrict__ feat, const float* __restrict__ rel_emb,
                             const float* __restrict__ ew, const int* __restrict__ src,
                             const int* __restrict__ dst, const int* __restrict__ rel,
                             float* __restrict__ out) {
    int wave = (blockIdx.x * blockDim.x + threadIdx.x) >> 6;
    int lane = threadIdx.x & 63;
    if (wave >= N_EDGES) return;
    const float* f = feat + (size_t)src[wave] * IN_DIM;
    const float* W = rel_emb + (size_t)rel[wave] * IN_DIM * OUT_DIM;
    float w = ew[wave];
    float a0 = 0.f, a1 = 0.f;
    for (int k = 0; k < IN_DIM; k++) {
        float fv = f[k];
        a0 += fv * W[k * OUT_DIM + lane];
        a1 += fv * W[k * OUT_DIM + 64 + lane];
    }
    int d = dst[wave];
    atomicAdd(&out[(size_t)d * OUT_DIM + lane], a0 * w);
    atomicAdd(&out[(size_t)d * OUT_DIM + 64 + lane], a1 * w);
}

extern "C" void kernel_launch(void* const* d_in, const int* in_sizes, int n_in,
                              void* d_out, int out_size, void* d_ws, size_t ws_size,
                              hipStream_t stream) {
    const float* feat    = (const float*)d_in[0];
    const float* rel_emb = (const float*)d_in[1];
    const float* ew      = (const float*)d_in[2];
    const int*   src     = (const int*)d_in[3];
    const int*   dst     = (const int*)d_in[4];
    const int*   rel     = (const int*)d_in[5];
    float* out = (float*)d_out;

    if (ws_size >= WS_NEED) {
        char* ws = (char*)d_ws;
        half_t* featH = (half_t*)(ws + WS_FEATH);
        half_t* WfT   = (half_t*)(ws + WS_WFT);
        uint2*  rec   = (uint2*)(ws + WS_REC);
        int*    off   = (int*)(ws + WS_OFF);
        int*    bsum  = (int*)(ws + WS_BSUM);
        // d_out scratch (dead after scatter; aggmm then writes out)
        int*    rank  = (int*)((char*)d_out + DO_RANK);
        int*    hist8 = (int*)((char*)d_out + DO_HIST8);
        int*    off8  = (int*)((char*)d_out + DO_OFF8);

        hipMemsetAsync(hist8, 0, (size_t)8 * NBINS3 * 4, stream);
        prep_kernel<<<PREP_BLOCKS, THREADS, 0, stream>>>(rel_emb, WfT, feat, featH,
                                                         dst, hist8, rank);
        scan1_kernel<<<NB3, 256, 0, stream>>>(hist8, bsum);
        scan2_kernel<<<1, 64, 0, stream>>>(bsum, off);
        scan3_kernel<<<NB3, 256, 0, stream>>>(hist8, bsum, off, off8);
        scatter_kernel<<<RANK_BLOCKS, THREADS, 0, stream>>>(dst, src, rel, ew,
                                                            rank, off8, rec);
        aggmm_kernel<<<FUSE_BLOCKS, AGG_THREADS, 0, stream>>>(featH, rec, off, WfT, out);
    } else {
        hipMemsetAsync(d_out, 0, (size_t)out_size * sizeof(float), stream);
        const long long total = (long long)N_EDGES * 64;
        const int blocks = (int)((total + THREADS - 1) / THREADS);
        naive_kernel<<<blocks, THREADS, 0, stream>>>(feat, rel_emb, ew, src, dst, rel, out);
    }
}